// Round 8
// baseline (184.038 us; speedup 1.0000x reference)
//
#include <hip/hip_runtime.h>

#define N_SAMP 16384
#define D_FEAT 64
#define TILE 128
#define NTILE 128                     // 128 tile-rows
#define SPLIT 12                      // blocks per row-pair
#define NPAIR (NTILE / 2)             // 64
#define NBLOCKS (NPAIR * SPLIT)       // 768 blocks = 3/CU resident
#define TPP (NTILE + 1)               // 129 tiles per pair (constant)
#define SEG_BASE (TPP / SPLIT)        // 10
#define SEG_REM (TPP % SPLIT)         // 9
#define BUFBYTES (TILE * D_FEAT * 2)  // 16 KiB per B buffer

typedef __attribute__((ext_vector_type(8))) short bf16x8;
typedef __attribute__((ext_vector_type(4))) float f32x4;
typedef __attribute__((ext_vector_type(2))) float f32x2;
typedef __attribute__((ext_vector_type(4))) unsigned short u16x4;

typedef __attribute__((address_space(3))) unsigned lds_u32_t;
typedef const __attribute__((address_space(1))) unsigned glb_u32_t;

__device__ __forceinline__ void load16_to_lds(const void* g, void* l) {
  __builtin_amdgcn_global_load_lds((glb_u32_t*)g, (lds_u32_t*)l, 16, 0, 0);
}

__device__ __forceinline__ unsigned short f2bf_rne(float f) {
  union { float f; unsigned u; } v;
  v.f = f;
  unsigned u = v.u;
  return (unsigned short)((u + 0x7FFFu + ((u >> 16) & 1u)) >> 16);
}

// Prepass: xb[i][k] = bf16(y_i * x[i][k]); blocks 0..63 also reduce
// {relu(alpha), relu(xi), y} and write a per-block triple via PLAIN STORES
// (no atomics -> no zero-init -> no memset dispatch).
__global__ __launch_bounds__(256) void prep_kernel(
    const float* __restrict__ x, const float* __restrict__ y,
    const float* __restrict__ alpha, const float* __restrict__ xi,
    unsigned short* __restrict__ xb, float4* __restrict__ psums) {
  int t = blockIdx.x * 256 + threadIdx.x;  // 0 .. 262143
  int base = t * 4;
  int row = base >> 6;  // D=64
  float yv = y[row];
  float4 v = *(const float4*)(x + base);
  u16x4 o;
  o.x = f2bf_rne(v.x * yv);
  o.y = f2bf_rne(v.y * yv);
  o.z = f2bf_rne(v.z * yv);
  o.w = f2bf_rne(v.w * yv);
  *(u16x4*)(xb + base) = o;

  if (blockIdx.x < (N_SAMP / 256)) {
    float a = fmaxf(alpha[t], 0.0f);
    float xr = fmaxf(xi[t], 0.0f);
    float yy = y[t];
#pragma unroll
    for (int off = 32; off > 0; off >>= 1) {
      a += __shfl_down(a, off, 64);
      xr += __shfl_down(xr, off, 64);
      yy += __shfl_down(yy, off, 64);
    }
    __shared__ float ra[4], rx[4], ry[4];
    int wv = threadIdx.x >> 6;
    if ((threadIdx.x & 63) == 0) {
      ra[wv] = a;
      rx[wv] = xr;
      ry[wv] = yy;
    }
    __syncthreads();
    if (threadIdx.x == 0)
      psums[blockIdx.x] =
          make_float4(ra[0] + ra[1] + ra[2] + ra[3],
                      rx[0] + rx[1] + rx[2] + rx[3],
                      ry[0] + ry[1] + ry[2] + ry[3], 0.0f);
  }
}

// R7 structure with occupancy enforced: launch_bounds(256,3) caps unified
// regs at ~170 (R7's 124+64=188 silently fell to 2 blocks/CU). bfr is read
// per-kc (16 VGPR live, was 32) to fit under the cap without spilling.
// Off-diag tiles carry weight (a_i + a_j); rsum defers a_i to one flush/row.
// T = y_i y_j (g+coeff) via acc-init; odd degree => T^d = y_i y_j K^d.
__global__ __launch_bounds__(256, 3) void tile_kernel(
    const unsigned short* __restrict__ xb,
    const float* __restrict__ alpha,
    const float* __restrict__ y,
    const int* __restrict__ coeffp,
    const int* __restrict__ degp,
    float* __restrict__ partials) {
  __shared__ unsigned short smA[TILE * D_FEAT];     // 16 KB
  __shared__ unsigned short smB[2][TILE * D_FEAT];  // 32 KB
  __shared__ float wred[4];

  const int tid = threadIdx.x;
  const int lane = tid & 63;
  const int wv = tid >> 6;  // wave 0..3
  const int wm = wv >> 1;   // wave row (0..1)
  const int wn = wv & 1;    // wave col (0..1)
  const int lr = lane & 15;
  const int q = lane >> 4;  // quad 0..3

  // ---- balanced schedule: pair p = {rows p, 127-p}, segment sb ----
  const int p = blockIdx.x / SPLIT;
  const int sb = blockIdx.x - p * SPLIT;
  const int i1 = p, i2 = NTILE - 1 - p;
  const int cnt1 = NTILE - p;  // tiles in row i1 (j = p..127)
  const int g0 = sb * SEG_BASE + (sb < SEG_REM ? sb : SEG_REM);
  const int gcnt = SEG_BASE + (sb < SEG_REM ? 1 : 0);

  const char* xbytes = (const char*)xb;
  char* smAb = (char*)smA;
  char* smBbase = (char*)smB;  // buffer k at smBbase + k*BUFBYTES

  const float fco = (float)coeffp[0];
  const int deg = degp[0];

  // per-thread staging offsets: 16B chunk (r,c) -> LDS slot r*8 + (c^(r&7))
  int goff[4];
#pragma unroll
  for (int it2 = 0; it2 < 4; ++it2) {
    int S = it2 * 256 + wv * 64 + lane;
    int r = S >> 3;
    int c = (S & 7) ^ (r & 7);
    goff[it2] = (r << 7) + (c << 4);
  }
  auto stage = [&](int rowtile, char* dst) {
    size_t tbase = ((size_t)rowtile) << 14;  // rowtile * 128 rows * 128 B
#pragma unroll
    for (int it2 = 0; it2 < 4; ++it2)
      load16_to_lds(xbytes + tbase + goff[it2],
                    dst + ((it2 * 256 + wv * 64) << 4));
  };

  f32x2 yr[4][2], ar[4][2];
  auto load_rows = [&](int ic) {
#pragma unroll
    for (int mt = 0; mt < 4; ++mt) {
      int idx = ic * TILE + wm * 64 + mt * 16 + q * 4;
      float4 yv = *(const float4*)(y + idx);
      float4 av = *(const float4*)(alpha + idx);
      yr[mt][0] = (f32x2){yv.x, yv.y};
      yr[mt][1] = (f32x2){yv.z, yv.w};
      ar[mt][0] = (f32x2){fmaxf(av.x, 0.0f), fmaxf(av.y, 0.0f)};
      ar[mt][1] = (f32x2){fmaxf(av.z, 0.0f), fmaxf(av.w, 0.0f)};
    }
  };

  bf16x8 af[4][2];
  auto read_af = [&]() {
#pragma unroll
    for (int mt = 0; mt < 4; ++mt) {
      int r = wm * 64 + mt * 16 + lr;
#pragma unroll
      for (int kc = 0; kc < 2; ++kc) {
        int c = kc * 4 + q;
        af[mt][kc] = *(const bf16x8*)(smAb + (r << 7) + ((c ^ (r & 7)) << 4));
      }
    }
  };

  f32x2 rsum[4][2];
#pragma unroll
  for (int mt = 0; mt < 4; ++mt)
    for (int h = 0; h < 2; ++h) rsum[mt][h] = (f32x2){0.0f, 0.0f};
  float lane_total = 0.0f;

  auto flush_rsum = [&]() {
#pragma unroll
    for (int mt = 0; mt < 4; ++mt) {
      f32x2 s = rsum[mt][0] * ar[mt][0] + rsum[mt][1] * ar[mt][1];
      lane_total += s.x + s.y;
      rsum[mt][0] = (f32x2){0.0f, 0.0f};
      rsum[mt][1] = (f32x2){0.0f, 0.0f};
    }
  };

  // ---- prologue: stage A(i of first tile) + B(first j) ----
  int ifirst = (g0 < cnt1) ? i1 : i2;
  int jfirst = (g0 < cnt1) ? (p + g0) : (i2 + (g0 - cnt1));
  stage(ifirst, smAb);
  stage(jfirst, smBbase);
  load_rows(ifirst);
  __syncthreads();
  read_af();
  // hazard guard: if iter 0 will restage A, af reads must be fenced first
  bool nswitch0 = (gcnt > 1) && ((g0 < cnt1) != (g0 + 1 < cnt1));
  if (nswitch0) __syncthreads();

  bool pend_switch = false;

  for (int it = 0; it < gcnt; ++it) {
    int g = g0 + it;
    int i = (g < cnt1) ? i1 : i2;
    int j = (g < cnt1) ? (p + g) : (i2 + (g - cnt1));
    char* bufc = smBbase + ((it & 1) * BUFBYTES);
    char* bufn = smBbase + (((it & 1) ^ 1) * BUFBYTES);

    if (pend_switch) {
      flush_rsum();      // old i's row weights
      load_rows(i);      // new row data
      read_af();         // A restaged last iter, drained by last barrier
      pend_switch = false;
    }

    // ---- prefetch next tile (in flight across this iter's compute) ----
    bool nswitch = false;
    if (it + 1 < gcnt) {
      int gn = g + 1;
      int inext = (gn < cnt1) ? i1 : i2;
      int jn = (gn < cnt1) ? (p + gn) : (i2 + (gn - cnt1));
      stage(jn, bufn);
      if (inext != i) {
        stage(inext, smAb);
        nswitch = true;
      }
    }

    // ---- column data ----
    float ycol[4], wcol[4];
#pragma unroll
    for (int nt = 0; nt < 4; ++nt) {
      int jj = j * TILE + wn * 64 + nt * 16 + lr;
      ycol[nt] = y[jj];
      wcol[nt] = fmaxf(alpha[jj], 0.0f);
    }

    // ---- acc init: y_i * y_j * coeff ----
    f32x4 acc[4][4];
#pragma unroll
    for (int mt = 0; mt < 4; ++mt) {
#pragma unroll
      for (int nt = 0; nt < 4; ++nt) {
        float s = ycol[nt] * fco;
        f32x2 lo = yr[mt][0] * s;
        f32x2 hi = yr[mt][1] * s;
        acc[mt][nt][0] = lo.x;
        acc[mt][nt][1] = lo.y;
        acc[mt][nt][2] = hi.x;
        acc[mt][nt][3] = hi.y;
      }
    }

    // ---- MFMA: per-kc B frags (16 VGPR live, not 32 — occupancy diet) ----
#pragma unroll
    for (int kc = 0; kc < 2; ++kc) {
      bf16x8 bfr[4];
#pragma unroll
      for (int nt = 0; nt < 4; ++nt) {
        int r = wn * 64 + nt * 16 + lr;
        int c = kc * 4 + q;
        bfr[nt] = *(const bf16x8*)(bufc + (r << 7) + ((c ^ (r & 7)) << 4));
      }
#pragma unroll
      for (int mt = 0; mt < 4; ++mt) {
#pragma unroll
        for (int nt = 0; nt < 4; ++nt) {
          acc[mt][nt] = __builtin_amdgcn_mfma_f32_16x16x32_bf16(
              af[mt][kc], bfr[nt], acc[mt][nt], 0, 0, 0);
        }
      }
    }

    // ---- epilogue ----
    bool diagonal = (j == i);
    if (deg == 3) {
      if (diagonal) {
#pragma unroll
        for (int nt = 0; nt < 4; ++nt) {
          f32x2 cs = {0.0f, 0.0f};
#pragma unroll
          for (int mt = 0; mt < 4; ++mt) {
#pragma unroll
            for (int h = 0; h < 2; ++h) {
              f32x2 T = {acc[mt][nt][2 * h], acc[mt][nt][2 * h + 1]};
              f32x2 T2 = T * T;
              cs += T2 * T;
            }
          }
          lane_total = fmaf(cs.x + cs.y, wcol[nt], lane_total);
        }
      } else {
#pragma unroll
        for (int nt = 0; nt < 4; ++nt) {
          f32x2 cs = {0.0f, 0.0f};
#pragma unroll
          for (int mt = 0; mt < 4; ++mt) {
#pragma unroll
            for (int h = 0; h < 2; ++h) {
              f32x2 T = {acc[mt][nt][2 * h], acc[mt][nt][2 * h + 1]};
              f32x2 T2 = T * T;
              f32x2 P = T2 * T;
              cs += P;
              rsum[mt][h] += P;  // row-weighted at flush (a_i fixed per row)
            }
          }
          lane_total = fmaf(cs.x + cs.y, wcol[nt], lane_total);
        }
      }
    } else {
      // generic-degree fallback (even degree restores y_i y_j sign)
#pragma unroll
      for (int nt = 0; nt < 4; ++nt) {
        float cs = 0.0f;
#pragma unroll
        for (int mt = 0; mt < 4; ++mt) {
          float ys[4] = {yr[mt][0].x, yr[mt][0].y, yr[mt][1].x, yr[mt][1].y};
          float as[4] = {ar[mt][0].x, ar[mt][0].y, ar[mt][1].x, ar[mt][1].y};
#pragma unroll
          for (int rg = 0; rg < 4; ++rg) {
            float T = acc[mt][nt][rg];
            float pw = 1.0f;
            for (int d = 0; d < deg; ++d) pw *= T;
            if (!(deg & 1)) pw *= ys[rg] * ycol[nt];
            cs += pw;
            if (!diagonal) lane_total += pw * as[rg];
          }
        }
        lane_total = fmaf(cs, wcol[nt], lane_total);
      }
    }

    __syncthreads();  // drains prefetch (long since landed) + orders LDS reuse
    pend_switch = nswitch;
  }

  flush_rsum();  // current segment's row weights

  // ---- one block reduce + one store per block ----
#pragma unroll
  for (int off = 32; off > 0; off >>= 1)
    lane_total += __shfl_down(lane_total, off, 64);
  if (lane == 0) wred[wv] = lane_total;
  __syncthreads();
  if (tid == 0)
    partials[blockIdx.x] = wred[0] + wred[1] + wred[2] + wred[3];
}

__global__ __launch_bounds__(256) void finalize_kernel(
    const float* __restrict__ partials,
    const float4* __restrict__ psums,
    const float* __restrict__ bp,
    const int* __restrict__ Cp,
    const int* __restrict__ lamp,
    float* __restrict__ out) {
  double tsum = 0.0, sa = 0.0, sx = 0.0, sy = 0.0;
  for (int i = threadIdx.x; i < NBLOCKS; i += 256) tsum += (double)partials[i];
  if (threadIdx.x < (N_SAMP / 256)) {  // 64 triples, wave 0 only
    float4 v = psums[threadIdx.x];
    sa = (double)v.x;
    sx = (double)v.y;
    sy = (double)v.z;
  }
#pragma unroll
  for (int off = 32; off > 0; off >>= 1) {
    tsum += __shfl_down(tsum, off, 64);
    sa += __shfl_down(sa, off, 64);
    sx += __shfl_down(sx, off, 64);
    sy += __shfl_down(sy, off, 64);
  }
  __shared__ double red[4][4];
  int wv = threadIdx.x >> 6;
  if ((threadIdx.x & 63) == 0) {
    red[wv][0] = tsum;
    red[wv][1] = sa;
    red[wv][2] = sx;
    red[wv][3] = sy;
  }
  __syncthreads();
  if (threadIdx.x == 0) {
    double T = red[0][0] + red[1][0] + red[2][0] + red[3][0];
    double A = red[0][1] + red[1][1] + red[2][1] + red[3][1];
    double X = red[0][2] + red[1][2] + red[2][2] + red[3][2];
    double Y = red[0][3] + red[1][3] + red[2][3] + red[3][3];
    double b = (double)bp[0];
    double Cc = (double)Cp[0];
    double lam = (double)lamp[0];
    double mean = (T + b * Y - (double)N_SAMP + X) / (double)N_SAMP;
    out[0] = (float)(0.5 * A + Cc * X + lam * mean);
  }
}

extern "C" void kernel_launch(void* const* d_in, const int* in_sizes, int n_in,
                              void* d_out, int out_size, void* d_ws,
                              size_t ws_size, hipStream_t stream) {
  const float* x = (const float*)d_in[0];
  const float* y = (const float*)d_in[1];
  const float* alpha = (const float*)d_in[2];
  const float* xi = (const float*)d_in[3];
  const float* b = (const float*)d_in[4];
  const int* coeff = (const int*)d_in[5];
  const int* degree = (const int*)d_in[6];
  const int* C = (const int*)d_in[7];
  const int* lambd = (const int*)d_in[8];

  unsigned short* xb = (unsigned short*)d_ws;  // 2 MB
  char* pbase = (char*)d_ws + (size_t)N_SAMP * D_FEAT * 2;
  float* partials = (float*)pbase;  // 768 floats
  float4* psums = (float4*)(pbase + ((NBLOCKS * 4 + 255) & ~255));  // 64 f4

  prep_kernel<<<(N_SAMP * D_FEAT) / (4 * 256), 256, 0, stream>>>(x, y, alpha,
                                                                 xi, xb, psums);

  tile_kernel<<<NBLOCKS, 256, 0, stream>>>(xb, alpha, y, coeff, degree,
                                           partials);

  finalize_kernel<<<1, 256, 0, stream>>>(partials, psums, b, C, lambd,
                                         (float*)d_out);
}

// Round 9
// 103.999 us; speedup vs baseline: 1.7696x; 1.7696x over previous
//
#include <hip/hip_runtime.h>

#define N_SAMP 16384
#define D_FEAT 64
#define TILE 128
#define NTILE 128                 // 128 tile-rows
#define SPLIT 8                   // wave-segments per row-pair
#define NPAIR (NTILE / 2)         // 64
#define NBLOCKS (NPAIR * SPLIT)   // 512 blocks = exactly 2/CU
#define TPP (NTILE + 1)           // 129 tiles per pair (constant)
#define SEG_BASE (TPP / SPLIT)    // 16
#define SEG_REM (TPP % SPLIT)     // 1

typedef __attribute__((ext_vector_type(8))) short bf16x8;
typedef __attribute__((ext_vector_type(4))) float f32x4;
typedef __attribute__((ext_vector_type(2))) float f32x2;
typedef __attribute__((ext_vector_type(4))) unsigned short u16x4;

typedef __attribute__((address_space(3))) unsigned lds_u32_t;
typedef const __attribute__((address_space(1))) unsigned glb_u32_t;

__device__ __forceinline__ void load16_to_lds(const void* g, void* l) {
  __builtin_amdgcn_global_load_lds((glb_u32_t*)g, (lds_u32_t*)l, 16, 0, 0);
}

__device__ __forceinline__ unsigned short f2bf_rne(float f) {
  union { float f; unsigned u; } v;
  v.f = f;
  unsigned u = v.u;
  return (unsigned short)((u + 0x7FFFu + ((u >> 16) & 1u)) >> 16);
}

// Prepass: xb[i][k] = bf16(y_i * x[i][k]); blocks 0..63 also reduce
// {relu(alpha), relu(xi), y} into per-block triples via plain stores.
__global__ __launch_bounds__(256) void prep_kernel(
    const float* __restrict__ x, const float* __restrict__ y,
    const float* __restrict__ alpha, const float* __restrict__ xi,
    unsigned short* __restrict__ xb, float4* __restrict__ psums) {
  int t = blockIdx.x * 256 + threadIdx.x;  // 0 .. 262143
  int base = t * 4;
  int row = base >> 6;  // D=64
  float yv = y[row];
  float4 v = *(const float4*)(x + base);
  u16x4 o;
  o.x = f2bf_rne(v.x * yv);
  o.y = f2bf_rne(v.y * yv);
  o.z = f2bf_rne(v.z * yv);
  o.w = f2bf_rne(v.w * yv);
  *(u16x4*)(xb + base) = o;

  if (blockIdx.x < (N_SAMP / 256)) {
    float a = fmaxf(alpha[t], 0.0f);
    float xr = fmaxf(xi[t], 0.0f);
    float yy = y[t];
#pragma unroll
    for (int off = 32; off > 0; off >>= 1) {
      a += __shfl_down(a, off, 64);
      xr += __shfl_down(xr, off, 64);
      yy += __shfl_down(yy, off, 64);
    }
    __shared__ float ra[4], rx[4], ry[4];
    int wv = threadIdx.x >> 6;
    if ((threadIdx.x & 63) == 0) {
      ra[wv] = a;
      rx[wv] = xr;
      ry[wv] = yy;
    }
    __syncthreads();
    if (threadIdx.x == 0)
      psums[blockIdx.x] =
          make_float4(ra[0] + ra[1] + ra[2] + ra[3],
                      rx[0] + rx[1] + rx[2] + rx[3],
                      ry[0] + ry[1] + ry[2] + ry[3], 0.0f);
  }
}

// BARRIER-FREE K-loop: each wave owns quadrant (wm,wn) of the block's tile
// sequence with a private 2x8KB double-buffered B chunk — no __syncthreads
// in the loop (R7's block-wide barrier+vmcnt(0) convoy was the ~75% stall).
// Per-wave buffer readiness via explicit s_waitcnt vmcnt(8): the prefetch's
// 8 loads stay in flight across MFMA+epilogue. A-frags direct from global
// (L2-hot; once per row switch). XOR swizzle applied on the GLOBAL address
// so LDS slot (r,c) = r*8 + (c^(r&7)) -> conflict-free ds_read_b128.
// Off-diag tiles weight (a_i + a_j); rsum defers a_i to one flush per row.
// T = y_i y_j (g+coeff) via acc-init; odd degree => T^d = y_i y_j K^d.
__global__ __launch_bounds__(256, 2) void tile_kernel(
    const unsigned short* __restrict__ xb,
    const float* __restrict__ alpha,
    const float* __restrict__ y,
    const int* __restrict__ coeffp,
    const int* __restrict__ degp,
    float* __restrict__ partials) {
  __shared__ unsigned short smB[4][2][64 * 64];  // 4 waves x 2 bufs x 8 KB
  __shared__ float wred[4];

  const int tid = threadIdx.x;
  const int lane = tid & 63;
  const int wv = tid >> 6;  // wave 0..3
  const int wm = wv >> 1;   // quadrant row (0..1)
  const int wn = wv & 1;    // quadrant col (0..1)
  const int lr = lane & 15;
  const int q = lane >> 4;  // quad 0..3

  // ---- balanced schedule: pair p = {rows p, 127-p}, segment sb ----
  const int p = blockIdx.x >> 3;
  const int sb = blockIdx.x & (SPLIT - 1);
  const int i1 = p, i2 = NTILE - 1 - p;
  const int cnt1 = NTILE - p;  // tiles in row i1 (j = p..127)
  const int g0 = sb * SEG_BASE + (sb < SEG_REM ? sb : SEG_REM);
  const int gcnt = SEG_BASE + (sb < SEG_REM ? 1 : 0);

  const char* xbytes = (const char*)xb;
  char* mybuf = (char*)smB + (wv << 14);  // 16 KB per wave

  const float fco = (float)coeffp[0];
  const int deg = degp[0];

  // global-side swizzle: lane carries chunk (r = L*8 + lane/8,
  // c = (lane&7) ^ (r&7)); HW scatters to base+lane*16 -> LDS slot r*8+c^..
  const int swz =
      ((lane >> 3) << 7) + (((lane & 7) ^ ((lane >> 3) & 7)) << 4);

  auto stage_wave = [&](int coltile, int k) {
    const char* gbase =
        xbytes + (((size_t)(coltile * TILE + wn * 64)) << 7) + swz;
    char* dst = mybuf + (k << 13);
#pragma unroll
    for (int L = 0; L < 8; ++L)
      load16_to_lds(gbase + (L << 10), dst + (L << 10));
  };

  f32x2 yr[4][2], ar[4][2];
  auto load_rows = [&](int ic) {
#pragma unroll
    for (int mt = 0; mt < 4; ++mt) {
      int idx = ic * TILE + wm * 64 + mt * 16 + q * 4;
      float4 yv = *(const float4*)(y + idx);
      float4 av = *(const float4*)(alpha + idx);
      yr[mt][0] = (f32x2){yv.x, yv.y};
      yr[mt][1] = (f32x2){yv.z, yv.w};
      ar[mt][0] = (f32x2){fmaxf(av.x, 0.0f), fmaxf(av.y, 0.0f)};
      ar[mt][1] = (f32x2){fmaxf(av.z, 0.0f), fmaxf(av.w, 0.0f)};
    }
  };

  bf16x8 af[4][2];
  auto read_af_g = [&](int rowtile) {
    const char* base = xbytes + (((size_t)(rowtile * TILE + wm * 64)) << 7);
#pragma unroll
    for (int mt = 0; mt < 4; ++mt) {
      int r = mt * 16 + lr;
#pragma unroll
      for (int kc = 0; kc < 2; ++kc)
        af[mt][kc] = *(const bf16x8*)(base + (r << 7) + ((kc * 4 + q) << 4));
    }
  };

  f32x2 rsum[4][2];
#pragma unroll
  for (int mt = 0; mt < 4; ++mt)
    for (int h = 0; h < 2; ++h) rsum[mt][h] = (f32x2){0.0f, 0.0f};
  float lane_total = 0.0f;

  auto flush_rsum = [&]() {
#pragma unroll
    for (int mt = 0; mt < 4; ++mt) {
      f32x2 s = rsum[mt][0] * ar[mt][0] + rsum[mt][1] * ar[mt][1];
      lane_total += s.x + s.y;
      rsum[mt][0] = (f32x2){0.0f, 0.0f};
      rsum[mt][1] = (f32x2){0.0f, 0.0f};
    }
  };

  // ---- prologue: first B chunk into buf 0; first row's A/y/alpha ----
  int jfirst = (g0 < cnt1) ? (p + g0) : (i2 + (g0 - cnt1));
  stage_wave(jfirst, 0);
  int icur = (g0 < cnt1) ? i1 : i2;
  load_rows(icur);
  read_af_g(icur);

  for (int it = 0; it < gcnt; ++it) {
    int g = g0 + it;
    int i = (g < cnt1) ? i1 : i2;
    int j = (g < cnt1) ? (p + g) : (i2 + (g - cnt1));
    char* bufc = mybuf + ((it & 1) << 13);

    if (i != icur) {
      flush_rsum();     // old row's a_i weights
      load_rows(i);
      read_af_g(i);     // global, L2-hot; rare (once per block typically)
      icur = i;
    }

    // ---- column y/alpha: issued BEFORE prefetch so their waits leave the
    // prefetch in flight ----
    float ycol[4], wcol[4];
#pragma unroll
    for (int nt = 0; nt < 4; ++nt) {
      int jj = j * TILE + wn * 64 + nt * 16 + lr;
      ycol[nt] = y[jj];
      wcol[nt] = fmaxf(alpha[jj], 0.0f);
    }

    // ---- prefetch next B chunk into the other buffer ----
    if (it + 1 < gcnt) {
      int gn = g + 1;
      int jn = (gn < cnt1) ? (p + gn) : (i2 + (gn - cnt1));
      stage_wave(jn, (it + 1) & 1);
      // drain everything older than the 8 prefetch loads (incl. bufc stage)
      __builtin_amdgcn_s_waitcnt(0x0F78);  // vmcnt(8)
    } else {
      __builtin_amdgcn_s_waitcnt(0x0F70);  // vmcnt(0): last tile, full drain
    }

    // ---- acc init: y_i * y_j * coeff ----
    f32x4 acc[4][4];
#pragma unroll
    for (int mt = 0; mt < 4; ++mt) {
#pragma unroll
      for (int nt = 0; nt < 4; ++nt) {
        float s = ycol[nt] * fco;
        f32x2 lo = yr[mt][0] * s;
        f32x2 hi = yr[mt][1] * s;
        acc[mt][nt][0] = lo.x;
        acc[mt][nt][1] = lo.y;
        acc[mt][nt][2] = hi.x;
        acc[mt][nt][3] = hi.y;
      }
    }

    // ---- MFMA: per-kc B frags from the wave-private chunk ----
#pragma unroll
    for (int kc = 0; kc < 2; ++kc) {
      bf16x8 bfr[4];
#pragma unroll
      for (int nt = 0; nt < 4; ++nt) {
        int rr = nt * 16 + lr;  // row within the 64-row chunk
        bfr[nt] = *(const bf16x8*)(bufc + (rr << 7) +
                                   (((kc * 4 + q) ^ (rr & 7)) << 4));
      }
#pragma unroll
      for (int mt = 0; mt < 4; ++mt) {
#pragma unroll
        for (int nt = 0; nt < 4; ++nt) {
          acc[mt][nt] = __builtin_amdgcn_mfma_f32_16x16x32_bf16(
              af[mt][kc], bfr[nt], acc[mt][nt], 0, 0, 0);
        }
      }
    }

    // ---- epilogue ----
    bool diagonal = (j == i);
    if (deg == 3) {
      if (diagonal) {
#pragma unroll
        for (int nt = 0; nt < 4; ++nt) {
          f32x2 cs = {0.0f, 0.0f};
#pragma unroll
          for (int mt = 0; mt < 4; ++mt) {
#pragma unroll
            for (int h = 0; h < 2; ++h) {
              f32x2 T = {acc[mt][nt][2 * h], acc[mt][nt][2 * h + 1]};
              f32x2 T2 = T * T;
              cs += T2 * T;
            }
          }
          lane_total = fmaf(cs.x + cs.y, wcol[nt], lane_total);
        }
      } else {
#pragma unroll
        for (int nt = 0; nt < 4; ++nt) {
          f32x2 cs = {0.0f, 0.0f};
#pragma unroll
          for (int mt = 0; mt < 4; ++mt) {
#pragma unroll
            for (int h = 0; h < 2; ++h) {
              f32x2 T = {acc[mt][nt][2 * h], acc[mt][nt][2 * h + 1]};
              f32x2 T2 = T * T;
              f32x2 P = T2 * T;
              cs += P;
              rsum[mt][h] += P;  // a_i applied at flush (fixed per row)
            }
          }
          lane_total = fmaf(cs.x + cs.y, wcol[nt], lane_total);
        }
      }
    } else {
      // generic-degree fallback (even degree restores y_i y_j sign)
#pragma unroll
      for (int nt = 0; nt < 4; ++nt) {
        float cs = 0.0f;
#pragma unroll
        for (int mt = 0; mt < 4; ++mt) {
          float ys[4] = {yr[mt][0].x, yr[mt][0].y, yr[mt][1].x, yr[mt][1].y};
          float as[4] = {ar[mt][0].x, ar[mt][0].y, ar[mt][1].x, ar[mt][1].y};
#pragma unroll
          for (int rg = 0; rg < 4; ++rg) {
            float T = acc[mt][nt][rg];
            float pw = 1.0f;
            for (int d = 0; d < deg; ++d) pw *= T;
            if (!(deg & 1)) pw *= ys[rg] * ycol[nt];
            cs += pw;
            if (!diagonal) lane_total += pw * as[rg];
          }
        }
        lane_total = fmaf(cs, wcol[nt], lane_total);
      }
    }
    // no barrier: buffer reuse is safe per-wave (ds_reads of buf n were
    // consumed two iterations ago, in order, within this wave)
  }

  flush_rsum();  // last row's a_i weights

  // ---- the only block sync: final 4-wave reduce ----
#pragma unroll
  for (int off = 32; off > 0; off >>= 1)
    lane_total += __shfl_down(lane_total, off, 64);
  if (lane == 0) wred[wv] = lane_total;
  __syncthreads();
  if (tid == 0)
    partials[blockIdx.x] = wred[0] + wred[1] + wred[2] + wred[3];
}

__global__ __launch_bounds__(256) void finalize_kernel(
    const float* __restrict__ partials,
    const float4* __restrict__ psums,
    const float* __restrict__ bp,
    const int* __restrict__ Cp,
    const int* __restrict__ lamp,
    float* __restrict__ out) {
  double tsum = 0.0, sa = 0.0, sx = 0.0, sy = 0.0;
  for (int i = threadIdx.x; i < NBLOCKS; i += 256) tsum += (double)partials[i];
  if (threadIdx.x < (N_SAMP / 256)) {  // 64 triples, wave 0 only
    float4 v = psums[threadIdx.x];
    sa = (double)v.x;
    sx = (double)v.y;
    sy = (double)v.z;
  }
#pragma unroll
  for (int off = 32; off > 0; off >>= 1) {
    tsum += __shfl_down(tsum, off, 64);
    sa += __shfl_down(sa, off, 64);
    sx += __shfl_down(sx, off, 64);
    sy += __shfl_down(sy, off, 64);
  }
  __shared__ double red[4][4];
  int wv = threadIdx.x >> 6;
  if ((threadIdx.x & 63) == 0) {
    red[wv][0] = tsum;
    red[wv][1] = sa;
    red[wv][2] = sx;
    red[wv][3] = sy;
  }
  __syncthreads();
  if (threadIdx.x == 0) {
    double T = red[0][0] + red[1][0] + red[2][0] + red[3][0];
    double A = red[0][1] + red[1][1] + red[2][1] + red[3][1];
    double X = red[0][2] + red[1][2] + red[2][2] + red[3][2];
    double Y = red[0][3] + red[1][3] + red[2][3] + red[3][3];
    double b = (double)bp[0];
    double Cc = (double)Cp[0];
    double lam = (double)lamp[0];
    double mean = (T + b * Y - (double)N_SAMP + X) / (double)N_SAMP;
    out[0] = (float)(0.5 * A + Cc * X + lam * mean);
  }
}

extern "C" void kernel_launch(void* const* d_in, const int* in_sizes, int n_in,
                              void* d_out, int out_size, void* d_ws,
                              size_t ws_size, hipStream_t stream) {
  const float* x = (const float*)d_in[0];
  const float* y = (const float*)d_in[1];
  const float* alpha = (const float*)d_in[2];
  const float* xi = (const float*)d_in[3];
  const float* b = (const float*)d_in[4];
  const int* coeff = (const int*)d_in[5];
  const int* degree = (const int*)d_in[6];
  const int* C = (const int*)d_in[7];
  const int* lambd = (const int*)d_in[8];

  unsigned short* xb = (unsigned short*)d_ws;  // 2 MB
  char* pbase = (char*)d_ws + (size_t)N_SAMP * D_FEAT * 2;
  float* partials = (float*)pbase;  // 512 floats
  float4* psums = (float4*)(pbase + ((NBLOCKS * 4 + 255) & ~255));  // 64 f4

  prep_kernel<<<(N_SAMP * D_FEAT) / (4 * 256), 256, 0, stream>>>(x, y, alpha,
                                                                 xi, xb, psums);

  tile_kernel<<<NBLOCKS, 256, 0, stream>>>(xb, alpha, y, coeff, degree,
                                           partials);

  finalize_kernel<<<1, 256, 0, stream>>>(partials, psums, b, C, lambd,
                                         (float*)d_out);
}